// Round 12
// baseline (287.543 us; speedup 1.0000x reference)
//
#include <hip/hip_runtime.h>
#include <hip/hip_bf16.h>

typedef _Float16 f16x8 __attribute__((ext_vector_type(8)));
typedef _Float16 f16x4 __attribute__((ext_vector_type(4)));
typedef float    f32x4 __attribute__((ext_vector_type(4)));

#define B_SZ 512
#define T_SZ 2048
#define D_SZ 256
#define TCHUNK 16
#define NCHUNK (T_SZ / TCHUNK)   // 128

// ---------- kernel 1: W_eff[e,k] = sum_d Wa[e,d]*Wi[d,k];  b_eff[e] = Wa[e,:]@(bi+bh) + ba[e]
// (r5 original, unchanged)
__global__ __launch_bounds__(256) void prep_kernel(
    const float* __restrict__ Wa, const float* __restrict__ Wi,
    const float* __restrict__ bi, const float* __restrict__ bh,
    const float* __restrict__ ba,
    _Float16* __restrict__ Weff, float* __restrict__ beff)
{
    int e = blockIdx.x;      // output row (256)
    int d = threadIdx.x;     // output col (256)
    float a0 = 0.f, a1 = 0.f, a2 = 0.f, a3 = 0.f;
    #pragma unroll 4
    for (int k = 0; k < 256; k += 4) {
        a0 = fmaf(Wa[e*256 + k    ], Wi[(k    )*256 + d], a0);
        a1 = fmaf(Wa[e*256 + k + 1], Wi[(k + 1)*256 + d], a1);
        a2 = fmaf(Wa[e*256 + k + 2], Wi[(k + 2)*256 + d], a2);
        a3 = fmaf(Wa[e*256 + k + 3], Wi[(k + 3)*256 + d], a3);
    }
    Weff[e*256 + d] = (_Float16)((a0 + a1) + (a2 + a3));

    __shared__ float red[4];
    float s = Wa[e*256 + d] * (bi[d] + bh[d]);
    s += __shfl_down(s, 32, 64);
    s += __shfl_down(s, 16, 64);
    s += __shfl_down(s,  8, 64);
    s += __shfl_down(s,  4, 64);
    s += __shfl_down(s,  2, 64);
    s += __shfl_down(s,  1, 64);
    if ((d & 63) == 0) red[d >> 6] = s;
    __syncthreads();
    if (d == 0) beff[e] = ba[e] + ((red[0] + red[1]) + (red[2] + red[3]));
}

// ---------- kernel 2: fused attention + LSTM cell, one block per batch.
// Attn main loop is EXACT r5 (264us champion): 8 waves x 32 cols, swapped MFMA
// (S^T), fp16 LDS double-buffer 2x8KB, reg-staged coalesced loads, lgkm-only
// SYNC. NEW: attention_output stays in LDS; the block finishes its batch's
// LSTM cell in a fused tail (h0=c0=0 => f gate & W_hh dead) and writes d_out
// directly — removes the serialized lstm kernel + ao HBM roundtrip.
__global__ __launch_bounds__(512, 4) void attn_kernel(
    const float* __restrict__ x,          // (B, T, D)
    const _Float16* __restrict__ Weff,    // (256, 256) row-major [e][k]
    const float* __restrict__ beff,       // (256)
    const float* __restrict__ Wih,        // (1024, 256)
    const float* __restrict__ bih,        // (1024)
    const float* __restrict__ bhh,        // (1024)
    float* __restrict__ out)              // h | h | c  (3 x 131072)
{
    const int b    = blockIdx.x;
    const int tid  = threadIdx.x;          // 0..511
    const int wave = tid >> 6;             // 0..7
    const int lane = tid & 63;
    const int l15  = lane & 15;
    const int lq   = lane >> 4;

    __shared__ _Float16 xs[2][TCHUNK * 256];  // 2 x 8 KB, swizzle: byte ^= (row&7)<<4
    char* xsb0 = reinterpret_cast<char*>(&xs[0][0]);
    char* xsb1 = reinterpret_cast<char*>(&xs[1][0]);

    // Weff fragments (A-operand after swap): lane holds Weff[e=base+l15][k=ks*32+lq*8+i]
    const int col0 = wave*32 + l15;
    const int col1 = col0 + 16;
    f16x8 bfA[8], bfB[8];
    #pragma unroll
    for (int ks = 0; ks < 8; ++ks) {
        bfA[ks] = *reinterpret_cast<const f16x8*>(&Weff[col0*256 + ks*32 + lq*8]);
        bfB[ks] = *reinterpret_cast<const f16x8*>(&Weff[col1*256 + ks*32 + lq*8]);
    }
    // bias per accumulator slot: e = wave*32 (+16) + lq*4 + r
    const f32x4 bcA = *reinterpret_cast<const f32x4*>(&beff[wave*32 + lq*4]);
    const f32x4 bcB = *reinterpret_cast<const f32x4*>(&beff[wave*32 + 16 + lq*4]);

    const float* xb = x + (size_t)b * T_SZ * D_SZ;

    // staging: thread covers row = tid>>5 (0..15), 8 floats at col (tid&31)*8
    const int srow = tid >> 5;
    const int scg  = tid & 31;
    const float* srcp = xb + (size_t)srow * 256 + scg * 8;
    const int swb = (srow*512 + scg*16) ^ ((srow & 7) << 4);

    #define LOADC(R, c)                                                            \
        {                                                                          \
            const float* p = srcp + (size_t)(c) * (TCHUNK * D_SZ);                 \
            R##0 = *reinterpret_cast<const f32x4*>(p);                             \
            R##1 = *reinterpret_cast<const f32x4*>(p + 4);                         \
        }

    #define WRITE(BUF, R)                                                          \
        {                                                                          \
            f16x8 h;                                                               \
            h[0] = (_Float16)R##0[0]; h[1] = (_Float16)R##0[1];                    \
            h[2] = (_Float16)R##0[2]; h[3] = (_Float16)R##0[3];                    \
            h[4] = (_Float16)R##1[0]; h[5] = (_Float16)R##1[1];                    \
            h[6] = (_Float16)R##1[2]; h[7] = (_Float16)R##1[3];                    \
            *reinterpret_cast<f16x8*>((BUF) + swb) = h;                            \
        }

    // lgkm drain (my LDS ops done) -> barrier; does NOT drain vmcnt (prefetch lives)
    #define SYNC()                                                                 \
        {                                                                          \
            asm volatile("s_waitcnt lgkmcnt(0)" ::: "memory");                     \
            __builtin_amdgcn_sched_barrier(0);                                     \
            __builtin_amdgcn_s_barrier();                                          \
        }

    #define COMPUTE(BUF)                                                           \
        {                                                                          \
            const int aswz  = (l15 & 7) << 4;                                      \
            const int abase = l15 * 512;                                           \
            f32x4 acc0 = {0.f, 0.f, 0.f, 0.f};                                     \
            f32x4 acc1 = {0.f, 0.f, 0.f, 0.f};                                     \
            _Pragma("unroll")                                                      \
            for (int ks = 0; ks < 8; ++ks) {                                       \
                int ab = abase + ((ks*64 + lq*16) ^ aswz);                         \
                f16x8 a = *reinterpret_cast<const f16x8*>((BUF) + ab);             \
                acc0 = __builtin_amdgcn_mfma_f32_16x16x32_f16(bfA[ks], a, acc0, 0, 0, 0); \
                acc1 = __builtin_amdgcn_mfma_f32_16x16x32_f16(bfB[ks], a, acc1, 0, 0, 0); \
            }                                                                      \
            /* epilogue: lane has t = l15, e = wave*32 (+16) + lq*4 + r */         \
            int eb0 = abase + (((wave*64      ) + lq*8) ^ aswz);                   \
            int eb1 = abase + (((wave*64 + 32 ) + lq*8) ^ aswz);                   \
            f16x4 xq0 = *reinterpret_cast<const f16x4*>((BUF) + eb0);              \
            f16x4 xq1 = *reinterpret_cast<const f16x4*>((BUF) + eb1);              \
            _Pragma("unroll")                                                      \
            for (int r = 0; r < 4; ++r) {                                          \
                {                                                                  \
                    float s = acc0[r] + bcA[r];                                    \
                    float attn = __builtin_amdgcn_rcpf(1.f + __expf(-s));          \
                    ao0[r] = fmaf(attn, (float)xq0[r], ao0[r]);                    \
                }                                                                  \
                {                                                                  \
                    float s = acc1[r] + bcB[r];                                    \
                    float attn = __builtin_amdgcn_rcpf(1.f + __expf(-s));          \
                    ao1[r] = fmaf(attn, (float)xq1[r], ao1[r]);                    \
                }                                                                  \
            }                                                                      \
        }

    f32x4 ao0 = {0.f, 0.f, 0.f, 0.f};
    f32x4 ao1 = {0.f, 0.f, 0.f, 0.f};
    f32x4 sA0, sA1, sB0, sB1;

    LOADC(sA, 0);
    LOADC(sB, 1);

    for (int c = 0; c < NCHUNK; c += 2) {
        WRITE(xsb0, sA);                 // vmcnt-waits sA only
        SYNC();                          // chunk c visible to all waves
        if (c + 2 < NCHUNK) LOADC(sA, c + 2);
        COMPUTE(xsb0);                   // chunk c
        WRITE(xsb1, sB);                 // other buffer: safe while others compute xsb0
        SYNC();                          // chunk c+1 visible
        if (c + 3 < NCHUNK) LOADC(sB, c + 3);
        COMPUTE(xsb1);                   // chunk c+1
    }

    // ---- sum over t: reduce across l15 within each lq group ----
    #pragma unroll
    for (int m = 1; m <= 8; m <<= 1) {
        #pragma unroll
        for (int r = 0; r < 4; ++r) {
            ao0[r] += __shfl_xor(ao0[r], m, 64);
            ao1[r] += __shfl_xor(ao1[r], m, 64);
        }
    }

    // stash attention_output in LDS. Safe: every wave's last xs[0] read was
    // drained (lgkmcnt 0) before the final in-loop barrier it already passed;
    // laggard waves only read xs[1] now, and we write xs[0].
    float* af = reinterpret_cast<float*>(xsb0);
    if (l15 == 0) {
        *reinterpret_cast<f32x4*>(&af[wave*32 +      lq*4]) = ao0;
        *reinterpret_cast<f32x4*>(&af[wave*32 + 16 + lq*4]) = ao1;
    }
    __syncthreads();   // af complete; all waves past COMPUTE(xsb1)

    // ---- fused LSTM cell: gates i,g,o (f dead, W_hh dead; gate rows i=0..255,
    // g=512..767, o=768..1023). 512 threads: j = tid&255, hf = k-half.
    const int j  = tid & 255;
    const int hf = tid >> 8;
    {
        const float* wi_ = Wih + (size_t)(      j) * 256 + hf*128;
        const float* wg_ = Wih + (size_t)(512 + j) * 256 + hf*128;
        const float* wo_ = Wih + (size_t)(768 + j) * 256 + hf*128;
        const float* ah  = af + hf*128;
        float gi = 0.f, gg = 0.f, go = 0.f;
        #pragma unroll 4
        for (int k = 0; k < 128; k += 4) {
            f32x4 w1 = *reinterpret_cast<const f32x4*>(wi_ + k);
            f32x4 w2 = *reinterpret_cast<const f32x4*>(wg_ + k);
            f32x4 w3 = *reinterpret_cast<const f32x4*>(wo_ + k);
            f32x4 av = *reinterpret_cast<const f32x4*>(ah + k);
            #pragma unroll
            for (int q = 0; q < 4; ++q) {
                gi = fmaf(w1[q], av[q], gi);
                gg = fmaf(w2[q], av[q], gg);
                go = fmaf(w3[q], av[q], go);
            }
        }
        float* pp = reinterpret_cast<float*>(xsb1);   // 3 x 512 partials (6 KB)
        pp[tid] = gi; pp[512 + tid] = gg; pp[1024 + tid] = go;
    }
    __syncthreads();
    if (tid < 256) {
        const float* pp = reinterpret_cast<const float*>(xsb1);
        float gi = pp[        tid] + pp[        tid + 256] + bih[      j] + bhh[      j];
        float gg = pp[ 512 +  tid] + pp[ 512 +  tid + 256] + bih[512 + j] + bhh[512 + j];
        float go = pp[1024 +  tid] + pp[1024 +  tid + 256] + bih[768 + j] + bhh[768 + j];
        float ig = 1.f / (1.f + __expf(-gi));
        float g  = tanhf(gg);
        float og = 1.f / (1.f + __expf(-go));
        float cc = ig * g;
        float hh = og * tanhf(cc);
        out[          b*256 + j] = hh;
        out[131072 +  b*256 + j] = hh;
        out[262144 +  b*256 + j] = cc;
    }

    #undef LOADC
    #undef WRITE
    #undef SYNC
    #undef COMPUTE
}

extern "C" void kernel_launch(void* const* d_in, const int* in_sizes, int n_in,
                              void* d_out, int out_size, void* d_ws, size_t ws_size,
                              hipStream_t stream) {
    const float* x    = (const float*)d_in[0];
    const float* Wi   = (const float*)d_in[1];
    const float* bi   = (const float*)d_in[2];
    // d_in[3] = Wh (dead: h0 = 0)
    const float* bh   = (const float*)d_in[4];
    const float* Wa   = (const float*)d_in[5];
    const float* ba   = (const float*)d_in[6];
    const float* W_ih = (const float*)d_in[7];
    const float* b_ih = (const float*)d_in[8];
    // d_in[9] = W_hh (dead: h0 = 0)
    const float* b_hh = (const float*)d_in[10];

    char* ws = (char*)d_ws;
    _Float16* Weff = (_Float16*)ws;                  // 128 KB
    float*    beff = (float*)(ws + 128*1024);        // 1 KB

    prep_kernel<<<256, 256, 0, stream>>>(Wa, Wi, bi, bh, ba, Weff, beff);
    attn_kernel<<<B_SZ, 512, 0, stream>>>(x, Weff, beff, W_ih, b_ih, b_hh,
                                          (float*)d_out);
}